// Round 13
// baseline (15.254 us; speedup 1.0000x reference)
//
#include <hip/hip_runtime.h>
#include <math.h>

namespace {
constexpr int Bn = 8192, Pn = 128, Dn = 128;
constexpr int BT = 64, PT = 32;                   // block tile: 64 b x 32 p
constexpr float MAXN = 1.0f - 1e-5f;              // (1-PROJ_EPS)/sqrt(c)
constexpr float CLAMPV = 16.63553233343869f;      // log(2/eps32)
constexpr float SMOOTH = 50.0f;
}

typedef float f2 __attribute__((ext_vector_type(2)));

#if defined(__has_builtin)
#if __has_builtin(__builtin_elementwise_fma)
#define FMA2(a, b, c) __builtin_elementwise_fma((a), (b), (c))
#else
static __device__ __forceinline__ f2 FMA2(f2 a, f2 b, f2 c) {
  c.x = fmaf(a.x, b.x, c.x); c.y = fmaf(a.y, b.y, c.y); return c;
}
#endif
#else
static __device__ __forceinline__ f2 FMA2(f2 a, f2 b, f2 c) {
  c.x = fmaf(a.x, b.x, c.x); c.y = fmaf(a.y, b.y, c.y); return c;
}
#endif

// ---------------- single fused kernel ----------------
// LDS plan (one 4160-f4 union = 66.6 KB):
//   phase A (pre-GEMM): slots 0..2047 x-tile (XOR swizzled);
//                       2048..2815 p-partials f32; 2816..3327 x-partials f32
//   phase B (GEMM):     0..2047 x-tile; 2048..3071 v-tile (overwrites dead scratch)
//   phase C (park):     0..4158 padded 8-partial park [team*520 + pg*65 + row]
__global__ __launch_bounds__(512, 4)
void fused_kernel(const float* __restrict__ x,
                  const float* __restrict__ weight,
                  const float* __restrict__ bias,
                  float* __restrict__ out) {
  __shared__ float4 lds4[4160];
  __shared__ double psum[96];
  __shared__ float x2A[64], fbA[64];
  __shared__ float bwA[32], iaA[32], soA[32];

  float* const scp = reinterpret_cast<float*>(lds4 + 2048);  // 6*512 f32
  float* const scx = reinterpret_cast<float*>(lds4 + 2816);  // 4*512 f32

  const int tid = threadIdx.x;
  const int team = tid >> 6;            // 0..7 : k-eighth (one wave)
  const int ti = tid & 63;
  const int txp = ti & 7;               // p-group (micro 4)
  const int tyy = ti >> 3;              // row-group (micro 8), 0..7
  const int b0 = blockIdx.x * BT;
  const int p0 = blockIdx.y * PT;
  const int rr = tid >> 5;              // 0..15: row within 16-row group
  const int cc = tid & 31;              // column chunk (float4)

  // ---- global loads (coalesced: 32 lanes span a row)
  float4 xv[4], wv[2], bv[2];
#pragma unroll
  for (int q = 0; q < 4; ++q)
    xv[q] = *reinterpret_cast<const float4*>(x + (size_t)(b0 + 16 * q + rr) * Dn + cc * 4);
#pragma unroll
  for (int q = 0; q < 2; ++q) {
    wv[q] = *reinterpret_cast<const float4*>(weight + (size_t)(p0 + 16 * q + rr) * Dn + cc * 4);
    bv[q] = *reinterpret_cast<const float4*>(bias + (size_t)(p0 + 16 * q + rr) * Dn + cc * 4);
  }

  // ---- stage x tile (swizzled) + write f32 stat partials (disjoint regions)
#pragma unroll
  for (int q = 0; q < 4; ++q) {
    const int r = 16 * q + rr;
    lds4[r * 32 + (cc ^ ((r >> 2) & 7))] = xv[q];
    float4 v = xv[q];
    scx[q * 512 + tid] = fmaf(v.x, v.x, fmaf(v.y, v.y, fmaf(v.z, v.z, v.w * v.w)));
  }
#pragma unroll
  for (int q = 0; q < 2; ++q) {
    float4 w = wv[q], b = bv[q];
    scp[(q * 3 + 0) * 512 + tid] = fmaf(b.x, b.x, fmaf(b.y, b.y, fmaf(b.z, b.z, b.w * b.w)));
    scp[(q * 3 + 1) * 512 + tid] = fmaf(b.x, w.x, fmaf(b.y, w.y, fmaf(b.z, w.z, b.w * w.w)));
    scp[(q * 3 + 2) * 512 + tid] = fmaf(w.x, w.x, fmaf(w.y, w.y, fmaf(w.z, w.z, w.w * w.w)));
  }
  __syncthreads();

  // ---- trees: 96 threads reduce p-partials -> psum; wave 4 reduces x rows
  if (tid < 96) {
    const int row = tid / 3;
    const int val = tid - 3 * row;
    const float4* base = reinterpret_cast<const float4*>(scp) +
                         ((row >> 4) * 3 + val) * 128 + (row & 15) * 8;
    double s = 0.0;
#pragma unroll
    for (int jj = 0; jj < 8; ++jj) {
      float4 f = base[(jj + tid) & 7];
      s += (double)f.x + (double)f.y + (double)f.z + (double)f.w;
    }
    psum[tid] = s;
  } else if (tid >= 256 && tid < 320) {
    const int r = tid - 256;
    const float4* base = reinterpret_cast<const float4*>(scx) +
                         (r >> 4) * 128 + (r & 15) * 8;
    double s = 0.0;
#pragma unroll
    for (int jj = 0; jj < 8; ++jj) {
      float4 f = base[(jj + tid) & 7];
      s += (double)f.x + (double)f.y + (double)f.z + (double)f.w;
    }
    x2A[r] = (float)s;
    fbA[r] = (float)(2.0 / (1.0 - s));
  }
  __syncthreads();

  // ---- v-build (finalize p-stats per thread from psum; f64 only where needed)
#pragma unroll
  for (int q = 0; q < 2; ++q) {
    const int r = 16 * q + rr;
    double nb2 = psum[3 * r + 0];
    double bwd = psum[3 * r + 1];
    double w2  = psum[3 * r + 2];
    double norm = sqrt(nb2);
    if (norm < 1e-15) norm = 1e-15;
    double scl = (norm > (double)MAXN) ? (double)MAXN / norm : 1.0;
    double p2 = nb2 * scl * scl;
    const float cxf = (float)(1.0 - p2);          // cancellation island in f64
    const float bwf = (float)(scl * bwd);
    const float k2f = 2.0f * bwf * (float)scl;
    float4 w = wv[q], b = bv[q], v;
    v.x = fmaf(cxf, w.x, k2f * b.x);
    v.y = fmaf(cxf, w.y, k2f * b.y);
    v.z = fmaf(cxf, w.z, k2f * b.z);
    v.w = fmaf(cxf, w.w, k2f * b.w);
    lds4[2048 + r * 32 + (cc ^ ((r >> 2) & 7))] = v;
    if (cc == 0) {
      float an = cxf * sqrtf((float)w2);
      if (an < 1e-15f) an = 1e-15f;
      bwA[r] = bwf;
      iaA[r] = 1.0f / an;
      soA[r] = 2.0f / cxf * an;                   // lambda_p * a_norm
    }
  }
  __syncthreads();

  // ---- GEMM: micro 8(b) x 4(p), one-wave teams over k-eighths, packed f32 FMA
  f2 acc2[8][4];
#pragma unroll
  for (int i = 0; i < 8; ++i)
#pragma unroll
    for (int j = 0; j < 4; ++j) acc2[i][j] = f2{0.0f, 0.0f};

#pragma unroll
  for (int kb = 0; kb < 4; ++kb) {
    const int k4 = team * 4 + kb;
    float4 vf[4];
    f2 vlo[4], vhi[4];
#pragma unroll
    for (int j = 0; j < 4; ++j) {
      vf[j] = lds4[2048 + (4 * txp + j) * 32 + (k4 ^ (txp & 7))];
      vlo[j] = f2{vf[j].x, vf[j].y};
      vhi[j] = f2{vf[j].z, vf[j].w};
    }
#pragma unroll
    for (int h = 0; h < 2; ++h) {
      const int swz = (2 * tyy + h) & 7;
#pragma unroll
      for (int u = 0; u < 4; ++u) {
        const int i = 4 * h + u;
        float4 xf = lds4[(8 * tyy + i) * 32 + (k4 ^ swz)];
        f2 xlo = f2{xf.x, xf.y};
        f2 xhi = f2{xf.z, xf.w};
#pragma unroll
        for (int j = 0; j < 4; ++j) {
          acc2[i][j] = FMA2(xlo, vlo[j], acc2[i][j]);
          acc2[i][j] = FMA2(xhi, vhi[j], acc2[i][j]);
        }
      }
    }
  }
  __syncthreads();

  // ---- park 8 k-partials: padded layout, <=2-way on write and read
#pragma unroll
  for (int i = 0; i < 8; ++i) {
    lds4[team * 520 + txp * 65 + (8 * tyy + i)] =
        make_float4(acc2[i][0].x + acc2[i][0].y, acc2[i][1].x + acc2[i][1].y,
                    acc2[i][2].x + acc2[i][2].y, acc2[i][3].x + acc2[i][3].y);
  }
  __syncthreads();

  // ---- merge + epilogue: thread owns (row = tid&63, pg = tid>>6)
  {
    const int row = tid & 63;
    const int pg = tid >> 6;
    float s[4] = {0.f, 0.f, 0.f, 0.f};
#pragma unroll
    for (int t = 0; t < 8; ++t) {
      float4 pp4 = lds4[t * 520 + pg * 65 + row];
      s[0] += pp4.x; s[1] += pp4.y; s[2] += pp4.z; s[3] += pp4.w;
    }
    const float x2i = x2A[row];
    const float fbi = fbA[row];
    const float opx = 1.0f + x2i;
    float res[4];
#pragma unroll
    for (int j = 0; j < 4; ++j) {
      const int pl = pg * 4 + j;
      float X = fmaf(-opx, bwA[pl], s[j]);       // <x,v> - (1+x2)*bw
      float arg = X * fbi * iaA[pl];             // Mobius denominator cancels
      float aa = fabsf(arg);
      float argc;
      if (aa <= CLAMPV - 0.35f) {
        argc = aa;                               // smooth_clamp == identity (exact fp32)
      } else if (aa >= CLAMPV + 0.35f) {
        argc = CLAMPV;                           // fully clamped (exact fp32)
      } else {
        float z = SMOOTH * (aa - CLAMPV);        // transition band: softplus corr
        float sp = (fmaxf(z, 0.0f) + log1pf(__expf(-fabsf(z)))) * (1.0f / SMOOTH);
        argc = aa - sp;
      }
      float r = __logf(argc + sqrtf(fmaf(argc, argc, 1.0f)));  // asinh, z>=0
      res[j] = copysignf(soA[pl] * r, arg);
    }
    *reinterpret_cast<float4*>(out + (size_t)(b0 + row) * Pn + p0 + pg * 4) =
        make_float4(res[0], res[1], res[2], res[3]);
  }
}

extern "C" void kernel_launch(void* const* d_in, const int* in_sizes, int n_in,
                              void* d_out, int out_size, void* d_ws, size_t ws_size,
                              hipStream_t stream) {
  const float* x = (const float*)d_in[0];
  const float* w = (const float*)d_in[1];
  const float* bias = (const float*)d_in[2];
  float* out = (float*)d_out;

  hipLaunchKernelGGL(fused_kernel, dim3(Bn / BT, Pn / PT), dim3(512), 0, stream,
                     x, w, bias, out);
}